// Round 1
// baseline (177.216 us; speedup 1.0000x reference)
//
#include <hip/hip_runtime.h>

// Modulated deformable conv, fp32 in/out. B=4, CIN=COUT=256, H=W=64, KS=3, PAD=1.
// R13: latency attack.
//  - k_all: T14 issue-early/consume-late on the xq gathers (loads for tap+2 issued
//    inside the tap-t MFMA region, consumed next iteration after the barrier drain),
//    wfrag B-fragments preloaded to registers per tap, sched_barrier(0) fences to
//    stop the compiler re-serializing (previous build: VGPR=60, fully serialized).
//  - k_pre: transpose rebuilt as float4-coalesced loads -> XOR-swizzled fp32 LDS
//    tile -> pack+transpose -> coalesced uint4 stores (was 64 serial scalar loads
//    per thread against cold HBM).
// ws: [xpairT 16 MB][wfrag 1.33 MB]; fallback to direct-fp32 path if ws too small.

#define WOFF_FRAG_OFF 589824
typedef unsigned short ushort_t;
typedef unsigned int   uint_t;

using short8 = __attribute__((ext_vector_type(8))) short;
using f32x4  = __attribute__((ext_vector_type(4))) float;

struct __attribute__((packed, aligned(4))) pairf { float x, y; };

__device__ inline ushort_t f2bf(float v) {
    unsigned u = __float_as_uint(v);
    unsigned r = u + 0x7fffu + ((u >> 16) & 1u);   // RNE (inputs finite)
    return (ushort_t)(r >> 16);
}
__device__ inline float bflo(uint_t u) { return __uint_as_float(u << 16); }
__device__ inline float bfhi(uint_t u) { return __uint_as_float(u & 0xffff0000u); }

// k_pre: blocks [0,XB): xpairT tile-transpose; [XB,XB+288): w_conv frags;
// [XB+288,XB+324): w_off frags. All global stores coalesced 16B.
__global__ __launch_bounds__(256) void k_pre(
    const float* __restrict__ x,
    const float* __restrict__ w_conv,
    const float* __restrict__ w_off,
    ushort_t* __restrict__ wfrag,
    uint_t* __restrict__ xpair,
    int XB)
{
    __shared__ __align__(16) float xt[256 * 32];   // [cin][i^swz] fp32 tile, 32 KB
    __shared__ float xcol[256];                    // 33rd column (i==32)
    const int bid = blockIdx.x;
    const int t = threadIdx.x;
    if (bid < XB) {
        // xqT[((b*4096 + idx)*256) + cin] = (bf16 x[b][cin][idx], bf16 x[b][cin][idx+1])
        const int b = bid >> 7;
        const int idx0 = (bid & 127) << 5;           // 32 idx rows per block
        const float* xb = x + (b << 20);
        // ---- load phase: fully coalesced float4, swizzled LDS store ----
#pragma unroll
        for (int r = 0; r < 8; ++r) {
            const int f = r * 256 + t;               // float4 id, 0..2047
            const int cin = f >> 3, k = f & 7;
            const float4 v = *(const float4*)&xb[(cin << 12) + idx0 + (k << 2)];
            const int swz = ((cin >> 2) & 7) << 2;   // XOR on i bits [2:4]
            *(float4*)&xt[(cin << 5) + ((k << 2) ^ swz)] = v;
        }
        // i==32 column: only a real value when the 32-window starts a row
        xcol[t] = ((idx0 & 63) == 0) ? xb[(t << 12) + idx0 + 32] : 0.f;
        __syncthreads();
        // ---- pack phase: transpose-read from LDS, coalesced 16B global stores ----
        uint_t* op = xpair + (((b << 12) + idx0) << 8);
#pragma unroll
        for (int r = 0; r < 8; ++r) {
            const int g = r * 256 + t;               // uint4 id, 0..2047
            const int il = g >> 6, c4 = (g & 63) << 2;
            uint_t o[4];
#pragma unroll
            for (int j = 0; j < 4; ++j) {
                const int c = c4 + j;
                const int swz = ((c >> 2) & 7) << 2;
                const float lo = xt[(c << 5) + (il ^ swz)];
                const float hi = (il < 31) ? xt[(c << 5) + ((il + 1) ^ swz)]
                                           : xcol[c];
                o[j] = (uint_t)f2bf(lo) | ((uint_t)f2bf(hi) << 16);
            }
            *(uint4*)(op + (il << 8) + c4) = make_uint4(o[0], o[1], o[2], o[3]);
        }
        return;
    }
    const int wb = bid - XB;
    if (wb < 288) {                                   // w_conv fragment rows
        const int i8 = wb * 256 + t;                  // 0..73727
        const int lane = i8 & 63;
        const int nt = (i8 >> 6) & 15;
        const int kt = i8 >> 10;                      // 0..71
        const int n = nt * 16 + (lane & 15);
        const int k0 = kt * 32 + ((lane >> 4) << 3);
        ushort_t v[8];
#pragma unroll
        for (int j = 0; j < 8; ++j) {
            const int kn = k0 + j;                    // tap-outer: kn = tap*256+cin
            const int cin = kn & 255, tap = kn >> 8;
            v[j] = f2bf(w_conv[n * 2304 + cin * 9 + tap]);
        }
        uint4 o;
        o.x = (uint_t)v[0] | ((uint_t)v[1] << 16);
        o.y = (uint_t)v[2] | ((uint_t)v[3] << 16);
        o.z = (uint_t)v[4] | ((uint_t)v[5] << 16);
        o.w = (uint_t)v[6] | ((uint_t)v[7] << 16);
        *(uint4*)(wfrag + (size_t)i8 * 8) = o;
    } else {                                          // w_off fragment rows (+pad)
        const int i8 = (wb - 288) * 256 + t;          // 0..9215
        const int lane = i8 & 63;
        const int nt = (i8 >> 6) & 1;
        const int kt = i8 >> 7;                       // 0..71
        const int n = nt * 16 + (lane & 15);
        const int k0 = kt * 32 + ((lane >> 4) << 3);
        ushort_t v[8];
#pragma unroll
        for (int j = 0; j < 8; ++j) {
            const int kn = k0 + j;
            const int cin = kn & 255, tap = kn >> 8;
            v[j] = (n < 27) ? f2bf(w_off[n * 2304 + cin * 9 + tap]) : (ushort_t)0;
        }
        uint4 o;
        o.x = (uint_t)v[0] | ((uint_t)v[1] << 16);
        o.y = (uint_t)v[2] | ((uint_t)v[3] << 16);
        o.z = (uint_t)v[4] | ((uint_t)v[5] << 16);
        o.w = (uint_t)v[6] | ((uint_t)v[7] << 16);
        *(uint4*)(wfrag + WOFF_FRAG_OFF + (size_t)i8 * 8) = o;
    }
}

// ---- k_all: block = 32 px x 256 couts, 512 thr = 8 waves, grid 512 ----
template<bool USE_PAIR>
__global__ __launch_bounds__(512, 4) void k_all(
    const float* __restrict__ x,
    const uint_t* __restrict__ xpair,
    const float* __restrict__ b_off,
    const ushort_t* __restrict__ wfrag,
    float* __restrict__ out)
{
    __shared__ short As[2][32 * 264];                // 33,792 B; px stride 264 shorts
    __shared__ __align__(16) float4 pwt[9 * 32];
    __shared__ __align__(16) int2   pidx[9 * 32];
    float* om_s = (float*)&As[0][0];                 // 32c x 32px fp32 alias

    const int bid = blockIdx.x;
    const int sid = ((bid & 7) << 6) | (bid >> 3);   // XCD-contiguous bands
    const int m0  = sid << 5;
    const int b   = m0 >> 12;
    const int h   = (m0 >> 6) & 63;
    const int wbase = m0 & 63;                        // 0 or 32
    const int tid  = threadIdx.x;
    const int lane = tid & 63;
    const int wv   = tid >> 6;                        // 0..7
    const int quad = lane >> 4;
    const int px   = tid & 31;                        // staging pixel
    const int slot = tid >> 5;                        // 0..15: 16 cins each

    const float*  xb = x + (b << 20);
    const uint_t* xq = xpair + (b << 20);
    const ushort_t* woffb = wfrag + WOFF_FRAG_OFF;

    // ================= phase 1: offset conv via MFMA =================
    const int m_w = wv & 1, nt_w = (wv >> 1) & 1;     // waves 0..3 cover 2m x 2nt
    f32x4 om_acc = {0.f, 0.f, 0.f, 0.f};

    if constexpr (USE_PAIR) {
        uint4 s1r[4]; bool s1v = false;
        auto issue1 = [&](int tap) {
            const int ky = (tap * 11) >> 5, kx = tap - ky * 3;
            const int yy = h + ky - 1;
            const int xx = wbase + px + kx - 1;
            const bool v = ((unsigned)yy < 64u) & ((unsigned)xx < 64u);
            const int idx = v ? (yy << 6) + xx : 0;
            const uint_t* p = xq + (idx << 8) + (slot << 4);
#pragma unroll
            for (int g = 0; g < 4; ++g) s1r[g] = *(const uint4*)(p + g * 4);
            s1v = v;
        };
        auto write1 = [&](int bufi) {
            const uint_t* rr = (const uint_t*)&s1r[0];
            uint_t o[8];
#pragma unroll
            for (int k = 0; k < 8; ++k) {
                const uint_t lo0 = s1v ? (rr[2 * k] & 0xffffu) : 0u;
                const uint_t lo1 = s1v ? (rr[2 * k + 1] & 0xffffu) : 0u;
                o[k] = lo0 | (lo1 << 16);
            }
            uint_t* dst = (uint_t*)&As[bufi][0] + px * 132 + slot * 8;
            *(uint4*)dst       = make_uint4(o[0], o[1], o[2], o[3]);
            *(uint4*)(dst + 4) = make_uint4(o[4], o[5], o[6], o[7]);
        };

        issue1(0);
        write1(0);                                   // one unavoidable prologue stall
        issue1(1);
        __syncthreads();
        for (int tap = 0; tap < 9; ++tap) {
            if (tap < 8) write1((tap + 1) & 1);      // consume tap+1 gathers
            if (wv < 4) {
                const short* cur = &As[tap & 1][0];
                short8 bfr[8];
#pragma unroll
                for (int k2 = 0; k2 < 8; ++k2)
                    bfr[k2] = *(const short8*)(woffb + (((tap * 8 + k2) * 2 + nt_w) * 64 + lane) * 8);
                __builtin_amdgcn_sched_barrier(0);
                if (tap < 7) issue1(tap + 2);        // gathers younger than bf loads
                __builtin_amdgcn_sched_barrier(0);
#pragma unroll
                for (int k2 = 0; k2 < 8; ++k2) {
                    const short8 a = *(const short8*)&cur[((m_w << 4) + (lane & 15)) * 264 + k2 * 32 + quad * 8];
                    om_acc = __builtin_amdgcn_mfma_f32_16x16x32_bf16(a, bfr[k2], om_acc, 0, 0, 0);
                }
            } else {
                if (tap < 7) issue1(tap + 2);        // hidden under barrier wait
            }
            __syncthreads();
        }
    } else {
        auto stage1 = [&](int tap, int bufi) {
            const int ky = (tap * 11) >> 5, kx = tap - ky * 3;
            const int yy = h + ky - 1;
            const int xx = wbase + px + kx - 1;
            const bool v = ((unsigned)yy < 64u) & ((unsigned)xx < 64u);
            const int idx = v ? (yy << 6) + xx : 0;
            uint_t lo16[16];
#pragma unroll
            for (int c = 0; c < 16; ++c) {
                const int cin = (slot << 4) + c;
                const float t0 = xb[(cin << 12) + idx];
                lo16[c] = v ? (uint_t)f2bf(t0) : 0u;
            }
            uint_t o[8];
#pragma unroll
            for (int k = 0; k < 8; ++k) o[k] = lo16[2 * k] | (lo16[2 * k + 1] << 16);
            uint_t* dst = (uint_t*)&As[bufi][0] + px * 132 + slot * 8;
            *(uint4*)dst       = make_uint4(o[0], o[1], o[2], o[3]);
            *(uint4*)(dst + 4) = make_uint4(o[4], o[5], o[6], o[7]);
        };
        auto mfma1 = [&](int tap) {
            if (wv < 4) {
                const short* cur = &As[tap & 1][0];
#pragma unroll
                for (int k2 = 0; k2 < 8; ++k2) {
                    const int ktg = tap * 8 + k2;
                    const short8 a = *(const short8*)&cur[((m_w << 4) + (lane & 15)) * 264 + k2 * 32 + quad * 8];
                    const short8 bf = *(const short8*)(woffb + ((ktg * 2 + nt_w) * 64 + lane) * 8);
                    om_acc = __builtin_amdgcn_mfma_f32_16x16x32_bf16(a, bf, om_acc, 0, 0, 0);
                }
            }
        };
        stage1(0, 0);
        __syncthreads();
        for (int tap = 0; tap < 9; ++tap) {
            if (tap < 8) stage1(tap + 1, (tap + 1) & 1);
            mfma1(tap);
            __syncthreads();
        }
    }

    if (wv < 4) {   // C/D: px = m_w*16 + quad*4 + reg; c = nt_w*16 + (lane&15)
        const int c = (nt_w << 4) + (lane & 15);
        *(f32x4*)&om_s[c * 32 + (m_w << 4) + (quad << 2)] = om_acc;
    }
    __syncthreads();

    // ================= phase 2: per-(tap,px) pair-gather params =================
    if (tid < 288) {
        const int p2 = tid & 31, tap = tid >> 5;
        const int ky = (tap * 11) >> 5, kx = tap - ky * 3;
        const float dyv = om_s[(2 * tap) * 32 + p2] + b_off[2 * tap];
        const float dxv = om_s[(2 * tap + 1) * 32 + p2] + b_off[2 * tap + 1];
        const float mo  = om_s[(18 + tap) * 32 + p2] + b_off[18 + tap];
        const float mv  = 1.f / (1.f + expf(-mo));
        const float py  = dyv + (float)(h - 1 + ky);
        const float pxf = dxv + (float)(wbase + p2 - 1 + kx);
        const float y0f = floorf(py), x0f = floorf(pxf);
        const float wy = py - y0f,    wx = pxf - x0f;
        const float vy0 = (y0f >=  0.f && y0f <= 63.f) ? 1.f : 0.f;
        const float vy1 = (y0f >= -1.f && y0f <= 62.f) ? 1.f : 0.f;
        const int ry0 = (int)fminf(fmaxf(y0f, 0.f), 63.f);
        const int ry1 = (int)fminf(fmaxf(y0f + 1.f, 0.f), 63.f);
        const float rw0 = (1.f - wy) * vy0 * mv;
        const float rw1 = wy * vy1 * mv;
        const bool in01 = (x0f >= 0.f && x0f <= 62.f);
        const float wa = in01 ? (1.f - wx) : ((x0f == -1.f) ? wx : 0.f);
        const float wb = in01 ? wx : ((x0f == 63.f) ? (1.f - wx) : 0.f);
        const int bx = (int)fminf(fmaxf(x0f, 0.f), 62.f);
        pwt[tid]  = make_float4(wa, wb, rw0, rw1);
        pidx[tid] = make_int2(ry0 * 64 + bx, ry1 * 64 + bx);
    }
    __syncthreads();

    // ================= phase 3: sampling + main GEMM =================
    f32x4 acc[2][2];
#pragma unroll
    for (int m = 0; m < 2; ++m)
#pragma unroll
        for (int nn = 0; nn < 2; ++nn) acc[m][nn] = f32x4{0.f, 0.f, 0.f, 0.f};

    const int nt_base = wv << 1;                      // wave's couts: wv*32..+31

    if constexpr (USE_PAIR) {
        uint4 r0[4], r1[4];
        auto issue3 = [&](int tap) {
            const int2 ii = pidx[tap * 32 + px];
            const uint_t* p0 = xq + (ii.x << 8) + (slot << 4);
            const uint_t* p1 = xq + (ii.y << 8) + (slot << 4);
#pragma unroll
            for (int g = 0; g < 4; ++g) {
                r0[g] = *(const uint4*)(p0 + g * 4);
                r1[g] = *(const uint4*)(p1 + g * 4);
            }
        };
        auto write3 = [&](int tap, int bufi) {
            const float4 wt = pwt[tap * 32 + px];
            const uint_t* a0 = (const uint_t*)&r0[0];
            const uint_t* a1 = (const uint_t*)&r1[0];
            uint_t o[8];
#pragma unroll
            for (int k = 0; k < 8; ++k) {
                ushort_t s[2];
#pragma unroll
                for (int u = 0; u < 2; ++u) {
                    const int c = 2 * k + u;
                    const float v = (bflo(a0[c]) * wt.x + bfhi(a0[c]) * wt.y) * wt.z
                                  + (bflo(a1[c]) * wt.x + bfhi(a1[c]) * wt.y) * wt.w;
                    s[u] = f2bf(v);
                }
                o[k] = (uint_t)s[0] | ((uint_t)s[1] << 16);
            }
            uint_t* dst = (uint_t*)&As[bufi][0] + px * 132 + slot * 8;
            *(uint4*)dst       = make_uint4(o[0], o[1], o[2], o[3]);
            *(uint4*)(dst + 4) = make_uint4(o[4], o[5], o[6], o[7]);
        };

        issue3(0);
        write3(0, 0);                                // overwrites om_s (dead now)
        issue3(1);
        __syncthreads();
        for (int tap = 0; tap < 9; ++tap) {
            if (tap < 8) write3(tap + 1, (tap + 1) & 1);
            {
                const short* cur = &As[tap & 1][0];
                short8 bfr[16];
#pragma unroll
                for (int k2 = 0; k2 < 8; ++k2)
#pragma unroll
                    for (int nn = 0; nn < 2; ++nn)
                        bfr[k2 * 2 + nn] = *(const short8*)(wfrag + (((tap * 8 + k2) * 16 + nt_base + nn) * 64 + lane) * 8);
                __builtin_amdgcn_sched_barrier(0);
                if (tap < 7) issue3(tap + 2);        // gathers younger than bf loads
                __builtin_amdgcn_sched_barrier(0);
#pragma unroll
                for (int k2 = 0; k2 < 8; ++k2) {
                    const short8 a0v = *(const short8*)&cur[(lane & 15) * 264 + k2 * 32 + quad * 8];
                    const short8 a1v = *(const short8*)&cur[((lane & 15) + 16) * 264 + k2 * 32 + quad * 8];
#pragma unroll
                    for (int nn = 0; nn < 2; ++nn) {
                        acc[0][nn] = __builtin_amdgcn_mfma_f32_16x16x32_bf16(a0v, bfr[k2 * 2 + nn], acc[0][nn], 0, 0, 0);
                        acc[1][nn] = __builtin_amdgcn_mfma_f32_16x16x32_bf16(a1v, bfr[k2 * 2 + nn], acc[1][nn], 0, 0, 0);
                    }
                }
            }
            __syncthreads();
        }
    } else {
        auto stage3 = [&](int tap, int bufi) {
            const float4 wt = pwt[tap * 32 + px];
            const int2   ii = pidx[tap * 32 + px];
            uint_t o[8];
#pragma unroll
            for (int k = 0; k < 8; ++k) {
                ushort_t s[2];
#pragma unroll
                for (int u = 0; u < 2; ++u) {
                    const int cin = (slot << 4) + 2 * k + u;
                    const pairf pa = *(const pairf*)(xb + (cin << 12) + ii.x);
                    const pairf pb = *(const pairf*)(xb + (cin << 12) + ii.y);
                    const float v = (pa.x * wt.x + pa.y * wt.y) * wt.z
                                  + (pb.x * wt.x + pb.y * wt.y) * wt.w;
                    s[u] = f2bf(v);
                }
                o[k] = (uint_t)s[0] | ((uint_t)s[1] << 16);
            }
            uint_t* dst = (uint_t*)&As[bufi][0] + px * 132 + slot * 8;
            *(uint4*)dst       = make_uint4(o[0], o[1], o[2], o[3]);
            *(uint4*)(dst + 4) = make_uint4(o[4], o[5], o[6], o[7]);
        };
        auto mfma3 = [&](int tap) {
            const short* cur = &As[tap & 1][0];
#pragma unroll
            for (int k2 = 0; k2 < 8; ++k2) {
                const int ktg = tap * 8 + k2;
                short8 a[2];
                a[0] = *(const short8*)&cur[(lane & 15) * 264 + k2 * 32 + quad * 8];
                a[1] = *(const short8*)&cur[((lane & 15) + 16) * 264 + k2 * 32 + quad * 8];
#pragma unroll
                for (int nn = 0; nn < 2; ++nn) {
                    const short8 bf = *(const short8*)(wfrag + ((ktg * 16 + nt_base + nn) * 64 + lane) * 8);
                    acc[0][nn] = __builtin_amdgcn_mfma_f32_16x16x32_bf16(a[0], bf, acc[0][nn], 0, 0, 0);
                    acc[1][nn] = __builtin_amdgcn_mfma_f32_16x16x32_bf16(a[1], bf, acc[1][nn], 0, 0, 0);
                }
            }
        };
        stage3(0, 0);
        __syncthreads();
        for (int tap = 0; tap < 9; ++tap) {
            if (tap < 8) stage3(tap + 1, (tap + 1) & 1);
            mfma3(tap);
            __syncthreads();
        }
    }

    // epilogue: w = wbase + m*16 + quad*4 + reg; cout n = wv*32 + nn*16 + (lane&15)
#pragma unroll
    for (int m = 0; m < 2; ++m) {
        const int w = wbase + (m << 4) + (quad << 2);
#pragma unroll
        for (int nn = 0; nn < 2; ++nn) {
            const int n = (wv << 5) + (nn << 4) + (lane & 15);
            float* op = out + (((size_t)((b << 8) + n)) << 12) + (h << 6) + w;
            *(f32x4*)op = acc[m][nn];
        }
    }
}

extern "C" void kernel_launch(void* const* d_in, const int* in_sizes, int n_in,
                              void* d_out, int out_size, void* d_ws, size_t ws_size,
                              hipStream_t stream) {
    const float* x      = (const float*)d_in[0];
    const float* w_off  = (const float*)d_in[1];
    const float* b_off  = (const float*)d_in[2];
    const float* w_conv = (const float*)d_in[3];
    float* out = (float*)d_out;

    const size_t need = 4194304ull * 4 + 663552ull * 2;   // 18,104,320 B
    const bool use_pair = (ws_size >= need);

    uint_t*   xpair = (uint_t*)d_ws;
    ushort_t* wfrag = use_pair ? (ushort_t*)((char*)d_ws + 4194304ull * 4)
                               : (ushort_t*)d_ws;
    const int XB = use_pair ? 512 : 0;

    hipLaunchKernelGGL(k_pre, dim3(XB + 324), dim3(256), 0, stream,
                       x, w_conv, w_off, wfrag, xpair, XB);
    if (use_pair)
        hipLaunchKernelGGL((k_all<true>), dim3(512), dim3(512), 0, stream,
                           x, xpair, b_off, wfrag, out);
    else
        hipLaunchKernelGGL((k_all<false>), dim3(512), dim3(512), 0, stream,
                           x, xpair, b_off, wfrag, out);
}

// Round 2
// 175.146 us; speedup vs baseline: 1.0118x; 1.0118x over previous
//
#include <hip/hip_runtime.h>

// Modulated deformable conv, fp32 in/out. B=4, CIN=COUT=256, H=W=64, KS=3, PAD=1.
// R14: R13 pipeline + amdgpu_waves_per_eu(4,4) on k_all.
//  R13 post-mortem: issue-early/consume-late prefetch SPILLED (WRITE_SIZE 44 MB vs
//  16.4 MB output, FETCH 92 MB, VGPR pinned at 64) -- backend targeted 8 waves/EU
//  and spilled the prefetch registers to scratch. Pinning waves/EU to exactly 4
//  gives the allocator its full 128-VGPR budget (2 blocks/CU, same grid-limited
//  occupancy as before).
// ws: [xpairT 16 MB][wfrag 1.33 MB]; fallback to direct-fp32 path if ws too small.

#define WOFF_FRAG_OFF 589824
typedef unsigned short ushort_t;
typedef unsigned int   uint_t;

using short8 = __attribute__((ext_vector_type(8))) short;
using f32x4  = __attribute__((ext_vector_type(4))) float;

struct __attribute__((packed, aligned(4))) pairf { float x, y; };

__device__ inline ushort_t f2bf(float v) {
    unsigned u = __float_as_uint(v);
    unsigned r = u + 0x7fffu + ((u >> 16) & 1u);   // RNE (inputs finite)
    return (ushort_t)(r >> 16);
}
__device__ inline float bflo(uint_t u) { return __uint_as_float(u << 16); }
__device__ inline float bfhi(uint_t u) { return __uint_as_float(u & 0xffff0000u); }

// k_pre: blocks [0,XB): xpairT tile-transpose; [XB,XB+288): w_conv frags;
// [XB+288,XB+324): w_off frags. All global stores coalesced 16B.
__global__ __launch_bounds__(256) void k_pre(
    const float* __restrict__ x,
    const float* __restrict__ w_conv,
    const float* __restrict__ w_off,
    ushort_t* __restrict__ wfrag,
    uint_t* __restrict__ xpair,
    int XB)
{
    __shared__ __align__(16) float xt[256 * 32];   // [cin][i^swz] fp32 tile, 32 KB
    __shared__ float xcol[256];                    // 33rd column (i==32)
    const int bid = blockIdx.x;
    const int t = threadIdx.x;
    if (bid < XB) {
        // xqT[((b*4096 + idx)*256) + cin] = (bf16 x[b][cin][idx], bf16 x[b][cin][idx+1])
        const int b = bid >> 7;
        const int idx0 = (bid & 127) << 5;           // 32 idx rows per block
        const float* xb = x + (b << 20);
        // ---- load phase: fully coalesced float4, swizzled LDS store ----
#pragma unroll
        for (int r = 0; r < 8; ++r) {
            const int f = r * 256 + t;               // float4 id, 0..2047
            const int cin = f >> 3, k = f & 7;
            const float4 v = *(const float4*)&xb[(cin << 12) + idx0 + (k << 2)];
            const int swz = ((cin >> 2) & 7) << 2;   // XOR on i bits [2:4]
            *(float4*)&xt[(cin << 5) + ((k << 2) ^ swz)] = v;
        }
        // i==32 column: only a real value when the 32-window starts a row
        xcol[t] = ((idx0 & 63) == 0) ? xb[(t << 12) + idx0 + 32] : 0.f;
        __syncthreads();
        // ---- pack phase: transpose-read from LDS, coalesced 16B global stores ----
        uint_t* op = xpair + (((b << 12) + idx0) << 8);
#pragma unroll
        for (int r = 0; r < 8; ++r) {
            const int g = r * 256 + t;               // uint4 id, 0..2047
            const int il = g >> 6, c4 = (g & 63) << 2;
            uint_t o[4];
#pragma unroll
            for (int j = 0; j < 4; ++j) {
                const int c = c4 + j;
                const int swz = ((c >> 2) & 7) << 2;
                const float lo = xt[(c << 5) + (il ^ swz)];
                const float hi = (il < 31) ? xt[(c << 5) + ((il + 1) ^ swz)]
                                           : xcol[c];
                o[j] = (uint_t)f2bf(lo) | ((uint_t)f2bf(hi) << 16);
            }
            *(uint4*)(op + (il << 8) + c4) = make_uint4(o[0], o[1], o[2], o[3]);
        }
        return;
    }
    const int wb = bid - XB;
    if (wb < 288) {                                   // w_conv fragment rows
        const int i8 = wb * 256 + t;                  // 0..73727
        const int lane = i8 & 63;
        const int nt = (i8 >> 6) & 15;
        const int kt = i8 >> 10;                      // 0..71
        const int n = nt * 16 + (lane & 15);
        const int k0 = kt * 32 + ((lane >> 4) << 3);
        ushort_t v[8];
#pragma unroll
        for (int j = 0; j < 8; ++j) {
            const int kn = k0 + j;                    // tap-outer: kn = tap*256+cin
            const int cin = kn & 255, tap = kn >> 8;
            v[j] = f2bf(w_conv[n * 2304 + cin * 9 + tap]);
        }
        uint4 o;
        o.x = (uint_t)v[0] | ((uint_t)v[1] << 16);
        o.y = (uint_t)v[2] | ((uint_t)v[3] << 16);
        o.z = (uint_t)v[4] | ((uint_t)v[5] << 16);
        o.w = (uint_t)v[6] | ((uint_t)v[7] << 16);
        *(uint4*)(wfrag + (size_t)i8 * 8) = o;
    } else {                                          // w_off fragment rows (+pad)
        const int i8 = (wb - 288) * 256 + t;          // 0..9215
        const int lane = i8 & 63;
        const int nt = (i8 >> 6) & 1;
        const int kt = i8 >> 7;                       // 0..71
        const int n = nt * 16 + (lane & 15);
        const int k0 = kt * 32 + ((lane >> 4) << 3);
        ushort_t v[8];
#pragma unroll
        for (int j = 0; j < 8; ++j) {
            const int kn = k0 + j;
            const int cin = kn & 255, tap = kn >> 8;
            v[j] = (n < 27) ? f2bf(w_off[n * 2304 + cin * 9 + tap]) : (ushort_t)0;
        }
        uint4 o;
        o.x = (uint_t)v[0] | ((uint_t)v[1] << 16);
        o.y = (uint_t)v[2] | ((uint_t)v[3] << 16);
        o.z = (uint_t)v[4] | ((uint_t)v[5] << 16);
        o.w = (uint_t)v[6] | ((uint_t)v[7] << 16);
        *(uint4*)(wfrag + WOFF_FRAG_OFF + (size_t)i8 * 8) = o;
    }
}

// ---- k_all: block = 32 px x 256 couts, 512 thr = 8 waves, grid 512 ----
template<bool USE_PAIR>
__global__ __launch_bounds__(512) __attribute__((amdgpu_waves_per_eu(4, 4)))
void k_all(
    const float* __restrict__ x,
    const uint_t* __restrict__ xpair,
    const float* __restrict__ b_off,
    const ushort_t* __restrict__ wfrag,
    float* __restrict__ out)
{
    __shared__ short As[2][32 * 264];                // 33,792 B; px stride 264 shorts
    __shared__ __align__(16) float4 pwt[9 * 32];
    __shared__ __align__(16) int2   pidx[9 * 32];
    float* om_s = (float*)&As[0][0];                 // 32c x 32px fp32 alias

    const int bid = blockIdx.x;
    const int sid = ((bid & 7) << 6) | (bid >> 3);   // XCD-contiguous bands
    const int m0  = sid << 5;
    const int b   = m0 >> 12;
    const int h   = (m0 >> 6) & 63;
    const int wbase = m0 & 63;                        // 0 or 32
    const int tid  = threadIdx.x;
    const int lane = tid & 63;
    const int wv   = tid >> 6;                        // 0..7
    const int quad = lane >> 4;
    const int px   = tid & 31;                        // staging pixel
    const int slot = tid >> 5;                        // 0..15: 16 cins each

    const float*  xb = x + (b << 20);
    const uint_t* xq = xpair + (b << 20);
    const ushort_t* woffb = wfrag + WOFF_FRAG_OFF;

    // ================= phase 1: offset conv via MFMA =================
    const int m_w = wv & 1, nt_w = (wv >> 1) & 1;     // waves 0..3 cover 2m x 2nt
    f32x4 om_acc = {0.f, 0.f, 0.f, 0.f};

    if constexpr (USE_PAIR) {
        uint4 s1r[4]; bool s1v = false;
        auto issue1 = [&](int tap) {
            const int ky = (tap * 11) >> 5, kx = tap - ky * 3;
            const int yy = h + ky - 1;
            const int xx = wbase + px + kx - 1;
            const bool v = ((unsigned)yy < 64u) & ((unsigned)xx < 64u);
            const int idx = v ? (yy << 6) + xx : 0;
            const uint_t* p = xq + (idx << 8) + (slot << 4);
#pragma unroll
            for (int g = 0; g < 4; ++g) s1r[g] = *(const uint4*)(p + g * 4);
            s1v = v;
        };
        auto write1 = [&](int bufi) {
            const uint_t* rr = (const uint_t*)&s1r[0];
            uint_t o[8];
#pragma unroll
            for (int k = 0; k < 8; ++k) {
                const uint_t lo0 = s1v ? (rr[2 * k] & 0xffffu) : 0u;
                const uint_t lo1 = s1v ? (rr[2 * k + 1] & 0xffffu) : 0u;
                o[k] = lo0 | (lo1 << 16);
            }
            uint_t* dst = (uint_t*)&As[bufi][0] + px * 132 + slot * 8;
            *(uint4*)dst       = make_uint4(o[0], o[1], o[2], o[3]);
            *(uint4*)(dst + 4) = make_uint4(o[4], o[5], o[6], o[7]);
        };

        issue1(0);
        write1(0);                                   // one unavoidable prologue stall
        issue1(1);
        __syncthreads();
        for (int tap = 0; tap < 9; ++tap) {
            if (tap < 8) write1((tap + 1) & 1);      // consume tap+1 gathers
            if (wv < 4) {
                const short* cur = &As[tap & 1][0];
                short8 bfr[8];
#pragma unroll
                for (int k2 = 0; k2 < 8; ++k2)
                    bfr[k2] = *(const short8*)(woffb + (((tap * 8 + k2) * 2 + nt_w) * 64 + lane) * 8);
                __builtin_amdgcn_sched_barrier(0);
                if (tap < 7) issue1(tap + 2);        // gathers younger than bf loads
                __builtin_amdgcn_sched_barrier(0);
#pragma unroll
                for (int k2 = 0; k2 < 8; ++k2) {
                    const short8 a = *(const short8*)&cur[((m_w << 4) + (lane & 15)) * 264 + k2 * 32 + quad * 8];
                    om_acc = __builtin_amdgcn_mfma_f32_16x16x32_bf16(a, bfr[k2], om_acc, 0, 0, 0);
                }
            } else {
                if (tap < 7) issue1(tap + 2);        // hidden under barrier wait
            }
            __syncthreads();
        }
    } else {
        auto stage1 = [&](int tap, int bufi) {
            const int ky = (tap * 11) >> 5, kx = tap - ky * 3;
            const int yy = h + ky - 1;
            const int xx = wbase + px + kx - 1;
            const bool v = ((unsigned)yy < 64u) & ((unsigned)xx < 64u);
            const int idx = v ? (yy << 6) + xx : 0;
            uint_t lo16[16];
#pragma unroll
            for (int c = 0; c < 16; ++c) {
                const int cin = (slot << 4) + c;
                const float t0 = xb[(cin << 12) + idx];
                lo16[c] = v ? (uint_t)f2bf(t0) : 0u;
            }
            uint_t o[8];
#pragma unroll
            for (int k = 0; k < 8; ++k) o[k] = lo16[2 * k] | (lo16[2 * k + 1] << 16);
            uint_t* dst = (uint_t*)&As[bufi][0] + px * 132 + slot * 8;
            *(uint4*)dst       = make_uint4(o[0], o[1], o[2], o[3]);
            *(uint4*)(dst + 4) = make_uint4(o[4], o[5], o[6], o[7]);
        };
        auto mfma1 = [&](int tap) {
            if (wv < 4) {
                const short* cur = &As[tap & 1][0];
#pragma unroll
                for (int k2 = 0; k2 < 8; ++k2) {
                    const int ktg = tap * 8 + k2;
                    const short8 a = *(const short8*)&cur[((m_w << 4) + (lane & 15)) * 264 + k2 * 32 + quad * 8];
                    const short8 bf = *(const short8*)(woffb + ((ktg * 2 + nt_w) * 64 + lane) * 8);
                    om_acc = __builtin_amdgcn_mfma_f32_16x16x32_bf16(a, bf, om_acc, 0, 0, 0);
                }
            }
        };
        stage1(0, 0);
        __syncthreads();
        for (int tap = 0; tap < 9; ++tap) {
            if (tap < 8) stage1(tap + 1, (tap + 1) & 1);
            mfma1(tap);
            __syncthreads();
        }
    }

    if (wv < 4) {   // C/D: px = m_w*16 + quad*4 + reg; c = nt_w*16 + (lane&15)
        const int c = (nt_w << 4) + (lane & 15);
        *(f32x4*)&om_s[c * 32 + (m_w << 4) + (quad << 2)] = om_acc;
    }
    __syncthreads();

    // ================= phase 2: per-(tap,px) pair-gather params =================
    if (tid < 288) {
        const int p2 = tid & 31, tap = tid >> 5;
        const int ky = (tap * 11) >> 5, kx = tap - ky * 3;
        const float dyv = om_s[(2 * tap) * 32 + p2] + b_off[2 * tap];
        const float dxv = om_s[(2 * tap + 1) * 32 + p2] + b_off[2 * tap + 1];
        const float mo  = om_s[(18 + tap) * 32 + p2] + b_off[18 + tap];
        const float mv  = 1.f / (1.f + expf(-mo));
        const float py  = dyv + (float)(h - 1 + ky);
        const float pxf = dxv + (float)(wbase + p2 - 1 + kx);
        const float y0f = floorf(py), x0f = floorf(pxf);
        const float wy = py - y0f,    wx = pxf - x0f;
        const float vy0 = (y0f >=  0.f && y0f <= 63.f) ? 1.f : 0.f;
        const float vy1 = (y0f >= -1.f && y0f <= 62.f) ? 1.f : 0.f;
        const int ry0 = (int)fminf(fmaxf(y0f, 0.f), 63.f);
        const int ry1 = (int)fminf(fmaxf(y0f + 1.f, 0.f), 63.f);
        const float rw0 = (1.f - wy) * vy0 * mv;
        const float rw1 = wy * vy1 * mv;
        const bool in01 = (x0f >= 0.f && x0f <= 62.f);
        const float wa = in01 ? (1.f - wx) : ((x0f == -1.f) ? wx : 0.f);
        const float wb = in01 ? wx : ((x0f == 63.f) ? (1.f - wx) : 0.f);
        const int bx = (int)fminf(fmaxf(x0f, 0.f), 62.f);
        pwt[tid]  = make_float4(wa, wb, rw0, rw1);
        pidx[tid] = make_int2(ry0 * 64 + bx, ry1 * 64 + bx);
    }
    __syncthreads();

    // ================= phase 3: sampling + main GEMM =================
    f32x4 acc[2][2];
#pragma unroll
    for (int m = 0; m < 2; ++m)
#pragma unroll
        for (int nn = 0; nn < 2; ++nn) acc[m][nn] = f32x4{0.f, 0.f, 0.f, 0.f};

    const int nt_base = wv << 1;                      // wave's couts: wv*32..+31

    if constexpr (USE_PAIR) {
        uint4 r0[4], r1[4];
        auto issue3 = [&](int tap) {
            const int2 ii = pidx[tap * 32 + px];
            const uint_t* p0 = xq + (ii.x << 8) + (slot << 4);
            const uint_t* p1 = xq + (ii.y << 8) + (slot << 4);
#pragma unroll
            for (int g = 0; g < 4; ++g) {
                r0[g] = *(const uint4*)(p0 + g * 4);
                r1[g] = *(const uint4*)(p1 + g * 4);
            }
        };
        auto write3 = [&](int tap, int bufi) {
            const float4 wt = pwt[tap * 32 + px];
            const uint_t* a0 = (const uint_t*)&r0[0];
            const uint_t* a1 = (const uint_t*)&r1[0];
            uint_t o[8];
#pragma unroll
            for (int k = 0; k < 8; ++k) {
                ushort_t s[2];
#pragma unroll
                for (int u = 0; u < 2; ++u) {
                    const int c = 2 * k + u;
                    const float v = (bflo(a0[c]) * wt.x + bfhi(a0[c]) * wt.y) * wt.z
                                  + (bflo(a1[c]) * wt.x + bfhi(a1[c]) * wt.y) * wt.w;
                    s[u] = f2bf(v);
                }
                o[k] = (uint_t)s[0] | ((uint_t)s[1] << 16);
            }
            uint_t* dst = (uint_t*)&As[bufi][0] + px * 132 + slot * 8;
            *(uint4*)dst       = make_uint4(o[0], o[1], o[2], o[3]);
            *(uint4*)(dst + 4) = make_uint4(o[4], o[5], o[6], o[7]);
        };

        issue3(0);
        write3(0, 0);                                // overwrites om_s (dead now)
        issue3(1);
        __syncthreads();
        for (int tap = 0; tap < 9; ++tap) {
            if (tap < 8) write3(tap + 1, (tap + 1) & 1);
            {
                const short* cur = &As[tap & 1][0];
                short8 bfr[16];
#pragma unroll
                for (int k2 = 0; k2 < 8; ++k2)
#pragma unroll
                    for (int nn = 0; nn < 2; ++nn)
                        bfr[k2 * 2 + nn] = *(const short8*)(wfrag + (((tap * 8 + k2) * 16 + nt_base + nn) * 64 + lane) * 8);
                __builtin_amdgcn_sched_barrier(0);
                if (tap < 7) issue3(tap + 2);        // gathers younger than bf loads
                __builtin_amdgcn_sched_barrier(0);
#pragma unroll
                for (int k2 = 0; k2 < 8; ++k2) {
                    const short8 a0v = *(const short8*)&cur[(lane & 15) * 264 + k2 * 32 + quad * 8];
                    const short8 a1v = *(const short8*)&cur[((lane & 15) + 16) * 264 + k2 * 32 + quad * 8];
#pragma unroll
                    for (int nn = 0; nn < 2; ++nn) {
                        acc[0][nn] = __builtin_amdgcn_mfma_f32_16x16x32_bf16(a0v, bfr[k2 * 2 + nn], acc[0][nn], 0, 0, 0);
                        acc[1][nn] = __builtin_amdgcn_mfma_f32_16x16x32_bf16(a1v, bfr[k2 * 2 + nn], acc[1][nn], 0, 0, 0);
                    }
                }
            }
            __syncthreads();
        }
    } else {
        auto stage3 = [&](int tap, int bufi) {
            const float4 wt = pwt[tap * 32 + px];
            const int2   ii = pidx[tap * 32 + px];
            uint_t o[8];
#pragma unroll
            for (int k = 0; k < 8; ++k) {
                ushort_t s[2];
#pragma unroll
                for (int u = 0; u < 2; ++u) {
                    const int cin = (slot << 4) + 2 * k + u;
                    const pairf pa = *(const pairf*)(xb + (cin << 12) + ii.x);
                    const pairf pb = *(const pairf*)(xb + (cin << 12) + ii.y);
                    const float v = (pa.x * wt.x + pa.y * wt.y) * wt.z
                                  + (pb.x * wt.x + pb.y * wt.y) * wt.w;
                    s[u] = f2bf(v);
                }
                o[k] = (uint_t)s[0] | ((uint_t)s[1] << 16);
            }
            uint_t* dst = (uint_t*)&As[bufi][0] + px * 132 + slot * 8;
            *(uint4*)dst       = make_uint4(o[0], o[1], o[2], o[3]);
            *(uint4*)(dst + 4) = make_uint4(o[4], o[5], o[6], o[7]);
        };
        auto mfma3 = [&](int tap) {
            const short* cur = &As[tap & 1][0];
#pragma unroll
            for (int k2 = 0; k2 < 8; ++k2) {
                const int ktg = tap * 8 + k2;
                short8 a[2];
                a[0] = *(const short8*)&cur[(lane & 15) * 264 + k2 * 32 + quad * 8];
                a[1] = *(const short8*)&cur[((lane & 15) + 16) * 264 + k2 * 32 + quad * 8];
#pragma unroll
                for (int nn = 0; nn < 2; ++nn) {
                    const short8 bf = *(const short8*)(wfrag + ((ktg * 16 + nt_base + nn) * 64 + lane) * 8);
                    acc[0][nn] = __builtin_amdgcn_mfma_f32_16x16x32_bf16(a[0], bf, acc[0][nn], 0, 0, 0);
                    acc[1][nn] = __builtin_amdgcn_mfma_f32_16x16x32_bf16(a[1], bf, acc[1][nn], 0, 0, 0);
                }
            }
        };
        stage3(0, 0);
        __syncthreads();
        for (int tap = 0; tap < 9; ++tap) {
            if (tap < 8) stage3(tap + 1, (tap + 1) & 1);
            mfma3(tap);
            __syncthreads();
        }
    }

    // epilogue: w = wbase + m*16 + quad*4 + reg; cout n = wv*32 + nn*16 + (lane&15)
#pragma unroll
    for (int m = 0; m < 2; ++m) {
        const int w = wbase + (m << 4) + (quad << 2);
#pragma unroll
        for (int nn = 0; nn < 2; ++nn) {
            const int n = (wv << 5) + (nn << 4) + (lane & 15);
            float* op = out + (((size_t)((b << 8) + n)) << 12) + (h << 6) + w;
            *(f32x4*)op = acc[m][nn];
        }
    }
}

extern "C" void kernel_launch(void* const* d_in, const int* in_sizes, int n_in,
                              void* d_out, int out_size, void* d_ws, size_t ws_size,
                              hipStream_t stream) {
    const float* x      = (const float*)d_in[0];
    const float* w_off  = (const float*)d_in[1];
    const float* b_off  = (const float*)d_in[2];
    const float* w_conv = (const float*)d_in[3];
    float* out = (float*)d_out;

    const size_t need = 4194304ull * 4 + 663552ull * 2;   // 18,104,320 B
    const bool use_pair = (ws_size >= need);

    uint_t*   xpair = (uint_t*)d_ws;
    ushort_t* wfrag = use_pair ? (ushort_t*)((char*)d_ws + 4194304ull * 4)
                               : (ushort_t*)d_ws;
    const int XB = use_pair ? 512 : 0;

    hipLaunchKernelGGL(k_pre, dim3(XB + 324), dim3(256), 0, stream,
                       x, w_conv, w_off, wfrag, xpair, XB);
    if (use_pair)
        hipLaunchKernelGGL((k_all<true>), dim3(512), dim3(512), 0, stream,
                           x, xpair, b_off, wfrag, out);
    else
        hipLaunchKernelGGL((k_all<false>), dim3(512), dim3(512), 0, stream,
                           x, xpair, b_off, wfrag, out);
}

// Round 3
// 153.656 us; speedup vs baseline: 1.1533x; 1.1399x over previous
//
#include <hip/hip_runtime.h>

// Modulated deformable conv, fp32 in/out. B=4, CIN=COUT=256, H=W=64, KS=3, PAD=1.
// R15: R12 structure + working prefetch.
//  R13/R14 post-mortem: prefetch arrays (uint4 r0[4] etc., lambda-captured, read
//  via reinterpret-cast) never SROA'd -> lived in scratch at ANY vgpr budget
//  (WRITE 44MB/FETCH 92MB scratch thrash, VGPR pinned 64). Fix: explicit named
//  uint4 scalars via macros, no arrays/casts/lambdas.
//  Also: __syncthreads drains vmcnt(0) -> in-loop barriers replaced with
//  s_waitcnt lgkmcnt(0) + raw s_barrier (LDS visibility only; gathers stay in
//  flight across the barrier, consumed next iteration).
//  k_pre transpose: 256 -> 512 thr/block (2x waves/CU, half-depth load chains).
// ws: [xpairT 16 MB][wfrag 1.33 MB]; fallback to direct-fp32 path if ws too small.

#define WOFF_FRAG_OFF 589824
typedef unsigned short ushort_t;
typedef unsigned int   uint_t;

using short8 = __attribute__((ext_vector_type(8))) short;
using f32x4  = __attribute__((ext_vector_type(4))) float;

struct __attribute__((packed, aligned(4))) pairf { float x, y; };

__device__ inline ushort_t f2bf(float v) {
    unsigned u = __float_as_uint(v);
    unsigned r = u + 0x7fffu + ((u >> 16) & 1u);   // RNE (inputs finite)
    return (ushort_t)(r >> 16);
}
__device__ inline float bflo(uint_t u) { return __uint_as_float(u << 16); }
__device__ inline float bfhi(uint_t u) { return __uint_as_float(u & 0xffff0000u); }

__device__ inline uint_t pk1(uint_t u0, uint_t u1, bool v) {
    return v ? ((u0 & 0xffffu) | (u1 << 16)) : 0u;
}
__device__ inline uint_t interp2(uint_t a0, uint_t a1, uint_t b0, uint_t b1, float4 wt) {
    const float v0 = (bflo(a0) * wt.x + bfhi(a0) * wt.y) * wt.z
                   + (bflo(a1) * wt.x + bfhi(a1) * wt.y) * wt.w;
    const float v1 = (bflo(b0) * wt.x + bfhi(b0) * wt.y) * wt.z
                   + (bflo(b1) * wt.x + bfhi(b1) * wt.y) * wt.w;
    return (uint_t)f2bf(v0) | ((uint_t)f2bf(v1) << 16);
}

// LDS-visibility barrier WITHOUT vmcnt drain: in-flight global loads survive.
#define BAR() do {                                              \
    asm volatile("s_waitcnt lgkmcnt(0)" ::: "memory");          \
    __builtin_amdgcn_s_barrier();                               \
    asm volatile("" ::: "memory");                              \
} while (0)

// k_pre: blocks [0,XB): xpairT tile-transpose; [XB,XB+144): w_conv frags;
// [XB+144,XB+162): w_off frags. All global stores coalesced 16B. 512 thr.
__global__ __launch_bounds__(512) void k_pre(
    const float* __restrict__ x,
    const float* __restrict__ w_conv,
    const float* __restrict__ w_off,
    ushort_t* __restrict__ wfrag,
    uint_t* __restrict__ xpair,
    int XB)
{
    __shared__ __align__(16) float xt[256 * 32];   // [cin][i^swz] fp32 tile, 32 KB
    __shared__ float xcol[256];                    // 33rd column (i==32)
    const int bid = blockIdx.x;
    const int t = threadIdx.x;
    if (bid < XB) {
        // xqT[((b*4096 + idx)*256) + cin] = (bf16 x[b][cin][idx], bf16 x[b][cin][idx+1])
        const int b = bid >> 7;
        const int idx0 = (bid & 127) << 5;           // 32 idx rows per block
        const float* xb = x + (b << 20);
        // ---- load phase: fully coalesced float4, swizzled LDS store ----
#pragma unroll
        for (int r = 0; r < 4; ++r) {
            const int f = r * 512 + t;               // float4 id, 0..2047
            const int cin = f >> 3, k = f & 7;
            const float4 v = *(const float4*)&xb[(cin << 12) + idx0 + (k << 2)];
            const int swz = ((cin >> 2) & 7) << 2;   // XOR on i bits [2:4]
            *(float4*)&xt[(cin << 5) + ((k << 2) ^ swz)] = v;
        }
        // i==32 column: only a real value when the 32-window starts a row
        if (t < 256)
            xcol[t] = ((idx0 & 63) == 0) ? xb[(t << 12) + idx0 + 32] : 0.f;
        __syncthreads();
        // ---- pack phase: transpose-read from LDS, coalesced 16B global stores ----
        uint_t* op = xpair + (((b << 12) + idx0) << 8);
#pragma unroll
        for (int r = 0; r < 4; ++r) {
            const int g = r * 512 + t;               // uint4 id, 0..2047
            const int il = g >> 6, c4 = (g & 63) << 2;
            uint_t o[4];
#pragma unroll
            for (int j = 0; j < 4; ++j) {
                const int c = c4 + j;
                const int swz = ((c >> 2) & 7) << 2;
                const float lo = xt[(c << 5) + (il ^ swz)];
                const float hi = (il < 31) ? xt[(c << 5) + ((il + 1) ^ swz)]
                                           : xcol[c];
                o[j] = (uint_t)f2bf(lo) | ((uint_t)f2bf(hi) << 16);
            }
            *(uint4*)(op + (il << 8) + c4) = make_uint4(o[0], o[1], o[2], o[3]);
        }
        return;
    }
    const int wb = bid - XB;
    if (wb < 144) {                                   // w_conv fragment rows
        const int i8 = wb * 512 + t;                  // 0..73727
        const int lane = i8 & 63;
        const int nt = (i8 >> 6) & 15;
        const int kt = i8 >> 10;                      // 0..71
        const int n = nt * 16 + (lane & 15);
        const int k0 = kt * 32 + ((lane >> 4) << 3);
        ushort_t v[8];
#pragma unroll
        for (int j = 0; j < 8; ++j) {
            const int kn = k0 + j;                    // tap-outer: kn = tap*256+cin
            const int cin = kn & 255, tap = kn >> 8;
            v[j] = f2bf(w_conv[n * 2304 + cin * 9 + tap]);
        }
        uint4 o;
        o.x = (uint_t)v[0] | ((uint_t)v[1] << 16);
        o.y = (uint_t)v[2] | ((uint_t)v[3] << 16);
        o.z = (uint_t)v[4] | ((uint_t)v[5] << 16);
        o.w = (uint_t)v[6] | ((uint_t)v[7] << 16);
        *(uint4*)(wfrag + (size_t)i8 * 8) = o;
    } else {                                          // w_off fragment rows (+pad)
        const int i8 = (wb - 144) * 512 + t;          // 0..9215
        const int lane = i8 & 63;
        const int nt = (i8 >> 6) & 1;
        const int kt = i8 >> 7;                       // 0..71
        const int n = nt * 16 + (lane & 15);
        const int k0 = kt * 32 + ((lane >> 4) << 3);
        ushort_t v[8];
#pragma unroll
        for (int j = 0; j < 8; ++j) {
            const int kn = k0 + j;
            const int cin = kn & 255, tap = kn >> 8;
            v[j] = (n < 27) ? f2bf(w_off[n * 2304 + cin * 9 + tap]) : (ushort_t)0;
        }
        uint4 o;
        o.x = (uint_t)v[0] | ((uint_t)v[1] << 16);
        o.y = (uint_t)v[2] | ((uint_t)v[3] << 16);
        o.z = (uint_t)v[4] | ((uint_t)v[5] << 16);
        o.w = (uint_t)v[6] | ((uint_t)v[7] << 16);
        *(uint4*)(wfrag + WOFF_FRAG_OFF + (size_t)i8 * 8) = o;
    }
}

// ---- prefetch macros: explicit named uint4 scalars (NO arrays -> SROA-safe) ----
#define ISSUE1(tap) do {                                                     \
    const int ky_ = ((tap) * 11) >> 5, kx_ = (tap) - ky_ * 3;                \
    const int yy_ = h + ky_ - 1;                                             \
    const int xx_ = wbase + px + kx_ - 1;                                    \
    s1v = ((unsigned)yy_ < 64u) & ((unsigned)xx_ < 64u);                     \
    const int idx_ = s1v ? (yy_ << 6) + xx_ : 0;                             \
    const uint_t* p_ = xq + (idx_ << 8) + (slot << 4);                       \
    s1a = *(const uint4*)(p_);      s1b = *(const uint4*)(p_ + 4);           \
    s1c = *(const uint4*)(p_ + 8);  s1d = *(const uint4*)(p_ + 12);          \
} while (0)

#define WRITE1(bufi) do {                                                    \
    uint_t* dst_ = (uint_t*)&As[bufi][0] + px * 132 + slot * 8;              \
    *(uint4*)dst_ = make_uint4(pk1(s1a.x, s1a.y, s1v), pk1(s1a.z, s1a.w, s1v), \
                               pk1(s1b.x, s1b.y, s1v), pk1(s1b.z, s1b.w, s1v)); \
    *(uint4*)(dst_ + 4) = make_uint4(pk1(s1c.x, s1c.y, s1v), pk1(s1c.z, s1c.w, s1v), \
                                     pk1(s1d.x, s1d.y, s1v), pk1(s1d.z, s1d.w, s1v)); \
} while (0)

#define ISSUE3(tap) do {                                                     \
    const int2 ii_ = pidx[(tap) * 32 + px];                                  \
    const uint_t* p0_ = xq + (ii_.x << 8) + (slot << 4);                     \
    const uint_t* p1_ = xq + (ii_.y << 8) + (slot << 4);                     \
    r0a = *(const uint4*)(p0_);      r0b = *(const uint4*)(p0_ + 4);         \
    r0c = *(const uint4*)(p0_ + 8);  r0d = *(const uint4*)(p0_ + 12);        \
    r1a = *(const uint4*)(p1_);      r1b = *(const uint4*)(p1_ + 4);         \
    r1c = *(const uint4*)(p1_ + 8);  r1d = *(const uint4*)(p1_ + 12);        \
} while (0)

#define WRITE3(tap, bufi) do {                                               \
    const float4 wt_ = pwt[(tap) * 32 + px];                                 \
    uint_t* dst_ = (uint_t*)&As[bufi][0] + px * 132 + slot * 8;              \
    *(uint4*)dst_ = make_uint4(                                              \
        interp2(r0a.x, r1a.x, r0a.y, r1a.y, wt_),                            \
        interp2(r0a.z, r1a.z, r0a.w, r1a.w, wt_),                            \
        interp2(r0b.x, r1b.x, r0b.y, r1b.y, wt_),                            \
        interp2(r0b.z, r1b.z, r0b.w, r1b.w, wt_));                           \
    *(uint4*)(dst_ + 4) = make_uint4(                                        \
        interp2(r0c.x, r1c.x, r0c.y, r1c.y, wt_),                            \
        interp2(r0c.z, r1c.z, r0c.w, r1c.w, wt_),                            \
        interp2(r0d.x, r1d.x, r0d.y, r1d.y, wt_),                            \
        interp2(r0d.z, r1d.z, r0d.w, r1d.w, wt_));                           \
} while (0)

// ---- k_all: block = 32 px x 256 couts, 512 thr = 8 waves, grid 512 ----
template<bool USE_PAIR>
__global__ __launch_bounds__(512, 4) void k_all(
    const float* __restrict__ x,
    const uint_t* __restrict__ xpair,
    const float* __restrict__ b_off,
    const ushort_t* __restrict__ wfrag,
    float* __restrict__ out)
{
    __shared__ short As[2][32 * 264];                // 33,792 B; px stride 264 shorts
    __shared__ __align__(16) float4 pwt[9 * 32];
    __shared__ __align__(16) int2   pidx[9 * 32];
    float* om_s = (float*)&As[0][0];                 // 32c x 32px fp32 alias

    const int bid = blockIdx.x;
    const int sid = ((bid & 7) << 6) | (bid >> 3);   // XCD-contiguous bands
    const int m0  = sid << 5;
    const int b   = m0 >> 12;
    const int h   = (m0 >> 6) & 63;
    const int wbase = m0 & 63;                        // 0 or 32
    const int tid  = threadIdx.x;
    const int lane = tid & 63;
    const int wv   = tid >> 6;                        // 0..7
    const int quad = lane >> 4;
    const int px   = tid & 31;                        // staging pixel
    const int slot = tid >> 5;                        // 0..15: 16 cins each

    const float*  xb = x + (b << 20);
    const uint_t* xq = xpair + (b << 20);
    const ushort_t* woffb = wfrag + WOFF_FRAG_OFF;

    // ================= phase 1: offset conv via MFMA =================
    const int m_w = wv & 1, nt_w = (wv >> 1) & 1;     // waves 0..3 cover 2m x 2nt
    f32x4 om_acc = {0.f, 0.f, 0.f, 0.f};

    if constexpr (USE_PAIR) {
        uint4 s1a, s1b, s1c, s1d; bool s1v = false;
        ISSUE1(0);
        WRITE1(0);                                   // one exposed prologue stall
        ISSUE1(1);
        BAR();
        for (int tap = 0; tap < 9; ++tap) {
            if (tap < 8) WRITE1((tap + 1) & 1);      // consume tap+1 gathers
            if (tap < 7) ISSUE1(tap + 2);            // in flight across MFMA+BAR
            if (wv < 4) {
                const short* cur = &As[tap & 1][0];
#pragma unroll
                for (int k2 = 0; k2 < 8; ++k2) {
                    const int ktg = tap * 8 + k2;
                    const short8 a = *(const short8*)&cur[((m_w << 4) + (lane & 15)) * 264 + k2 * 32 + quad * 8];
                    const short8 bf = *(const short8*)(woffb + ((ktg * 2 + nt_w) * 64 + lane) * 8);
                    om_acc = __builtin_amdgcn_mfma_f32_16x16x32_bf16(a, bf, om_acc, 0, 0, 0);
                }
            }
            BAR();
        }
    } else {
        auto stage1 = [&](int tap, int bufi) {
            const int ky = (tap * 11) >> 5, kx = tap - ky * 3;
            const int yy = h + ky - 1;
            const int xx = wbase + px + kx - 1;
            const bool v = ((unsigned)yy < 64u) & ((unsigned)xx < 64u);
            const int idx = v ? (yy << 6) + xx : 0;
            uint_t lo16[16];
#pragma unroll
            for (int c = 0; c < 16; ++c) {
                const int cin = (slot << 4) + c;
                const float t0 = xb[(cin << 12) + idx];
                lo16[c] = v ? (uint_t)f2bf(t0) : 0u;
            }
            uint_t o[8];
#pragma unroll
            for (int k = 0; k < 8; ++k) o[k] = lo16[2 * k] | (lo16[2 * k + 1] << 16);
            uint_t* dst = (uint_t*)&As[bufi][0] + px * 132 + slot * 8;
            *(uint4*)dst       = make_uint4(o[0], o[1], o[2], o[3]);
            *(uint4*)(dst + 4) = make_uint4(o[4], o[5], o[6], o[7]);
        };
        auto mfma1 = [&](int tap) {
            if (wv < 4) {
                const short* cur = &As[tap & 1][0];
#pragma unroll
                for (int k2 = 0; k2 < 8; ++k2) {
                    const int ktg = tap * 8 + k2;
                    const short8 a = *(const short8*)&cur[((m_w << 4) + (lane & 15)) * 264 + k2 * 32 + quad * 8];
                    const short8 bf = *(const short8*)(woffb + ((ktg * 2 + nt_w) * 64 + lane) * 8);
                    om_acc = __builtin_amdgcn_mfma_f32_16x16x32_bf16(a, bf, om_acc, 0, 0, 0);
                }
            }
        };
        stage1(0, 0);
        __syncthreads();
        for (int tap = 0; tap < 9; ++tap) {
            if (tap < 8) stage1(tap + 1, (tap + 1) & 1);
            mfma1(tap);
            __syncthreads();
        }
    }

    if (wv < 4) {   // C/D: px = m_w*16 + quad*4 + reg; c = nt_w*16 + (lane&15)
        const int c = (nt_w << 4) + (lane & 15);
        *(f32x4*)&om_s[c * 32 + (m_w << 4) + (quad << 2)] = om_acc;
    }
    __syncthreads();

    // ================= phase 2: per-(tap,px) pair-gather params =================
    if (tid < 288) {
        const int p2 = tid & 31, tap = tid >> 5;
        const int ky = (tap * 11) >> 5, kx = tap - ky * 3;
        const float dyv = om_s[(2 * tap) * 32 + p2] + b_off[2 * tap];
        const float dxv = om_s[(2 * tap + 1) * 32 + p2] + b_off[2 * tap + 1];
        const float mo  = om_s[(18 + tap) * 32 + p2] + b_off[18 + tap];
        const float mv  = 1.f / (1.f + expf(-mo));
        const float py  = dyv + (float)(h - 1 + ky);
        const float pxf = dxv + (float)(wbase + p2 - 1 + kx);
        const float y0f = floorf(py), x0f = floorf(pxf);
        const float wy = py - y0f,    wx = pxf - x0f;
        const float vy0 = (y0f >=  0.f && y0f <= 63.f) ? 1.f : 0.f;
        const float vy1 = (y0f >= -1.f && y0f <= 62.f) ? 1.f : 0.f;
        const int ry0 = (int)fminf(fmaxf(y0f, 0.f), 63.f);
        const int ry1 = (int)fminf(fmaxf(y0f + 1.f, 0.f), 63.f);
        const float rw0 = (1.f - wy) * vy0 * mv;
        const float rw1 = wy * vy1 * mv;
        const bool in01 = (x0f >= 0.f && x0f <= 62.f);
        const float wa = in01 ? (1.f - wx) : ((x0f == -1.f) ? wx : 0.f);
        const float wb = in01 ? wx : ((x0f == 63.f) ? (1.f - wx) : 0.f);
        const int bx = (int)fminf(fmaxf(x0f, 0.f), 62.f);
        pwt[tid]  = make_float4(wa, wb, rw0, rw1);
        pidx[tid] = make_int2(ry0 * 64 + bx, ry1 * 64 + bx);
    }
    __syncthreads();

    // ================= phase 3: sampling + main GEMM =================
    f32x4 acc[2][2];
#pragma unroll
    for (int m = 0; m < 2; ++m)
#pragma unroll
        for (int nn = 0; nn < 2; ++nn) acc[m][nn] = f32x4{0.f, 0.f, 0.f, 0.f};

    const int nt_base = wv << 1;                      // wave's couts: wv*32..+31

    if constexpr (USE_PAIR) {
        uint4 r0a, r0b, r0c, r0d, r1a, r1b, r1c, r1d;
        ISSUE3(0);
        WRITE3(0, 0);                                // overwrites om_s (dead now)
        ISSUE3(1);
        BAR();
        for (int tap = 0; tap < 9; ++tap) {
            if (tap < 8) WRITE3(tap + 1, (tap + 1) & 1);
            if (tap < 7) ISSUE3(tap + 2);            // in flight across MFMA+BAR
            {
                const short* cur = &As[tap & 1][0];
#pragma unroll
                for (int k2 = 0; k2 < 8; ++k2) {
                    const int ktg = tap * 8 + k2;
                    const short8 a0v = *(const short8*)&cur[(lane & 15) * 264 + k2 * 32 + quad * 8];
                    const short8 a1v = *(const short8*)&cur[((lane & 15) + 16) * 264 + k2 * 32 + quad * 8];
#pragma unroll
                    for (int nn = 0; nn < 2; ++nn) {
                        const short8 bf = *(const short8*)(wfrag + ((ktg * 16 + nt_base + nn) * 64 + lane) * 8);
                        acc[0][nn] = __builtin_amdgcn_mfma_f32_16x16x32_bf16(a0v, bf, acc[0][nn], 0, 0, 0);
                        acc[1][nn] = __builtin_amdgcn_mfma_f32_16x16x32_bf16(a1v, bf, acc[1][nn], 0, 0, 0);
                    }
                }
            }
            BAR();
        }
    } else {
        auto stage3 = [&](int tap, int bufi) {
            const float4 wt = pwt[tap * 32 + px];
            const int2   ii = pidx[tap * 32 + px];
            uint_t o[8];
#pragma unroll
            for (int k = 0; k < 8; ++k) {
                ushort_t s[2];
#pragma unroll
                for (int u = 0; u < 2; ++u) {
                    const int cin = (slot << 4) + 2 * k + u;
                    const pairf pa = *(const pairf*)(xb + (cin << 12) + ii.x);
                    const pairf pb = *(const pairf*)(xb + (cin << 12) + ii.y);
                    const float v = (pa.x * wt.x + pa.y * wt.y) * wt.z
                                  + (pb.x * wt.x + pb.y * wt.y) * wt.w;
                    s[u] = f2bf(v);
                }
                o[k] = (uint_t)s[0] | ((uint_t)s[1] << 16);
            }
            uint_t* dst = (uint_t*)&As[bufi][0] + px * 132 + slot * 8;
            *(uint4*)dst       = make_uint4(o[0], o[1], o[2], o[3]);
            *(uint4*)(dst + 4) = make_uint4(o[4], o[5], o[6], o[7]);
        };
        auto mfma3 = [&](int tap) {
            const short* cur = &As[tap & 1][0];
#pragma unroll
            for (int k2 = 0; k2 < 8; ++k2) {
                const int ktg = tap * 8 + k2;
                short8 a[2];
                a[0] = *(const short8*)&cur[(lane & 15) * 264 + k2 * 32 + quad * 8];
                a[1] = *(const short8*)&cur[((lane & 15) + 16) * 264 + k2 * 32 + quad * 8];
#pragma unroll
                for (int nn = 0; nn < 2; ++nn) {
                    const short8 bf = *(const short8*)(wfrag + ((ktg * 16 + nt_base + nn) * 64 + lane) * 8);
                    acc[0][nn] = __builtin_amdgcn_mfma_f32_16x16x32_bf16(a[0], bf, acc[0][nn], 0, 0, 0);
                    acc[1][nn] = __builtin_amdgcn_mfma_f32_16x16x32_bf16(a[1], bf, acc[1][nn], 0, 0, 0);
                }
            }
        };
        stage3(0, 0);
        __syncthreads();
        for (int tap = 0; tap < 9; ++tap) {
            if (tap < 8) stage3(tap + 1, (tap + 1) & 1);
            mfma3(tap);
            __syncthreads();
        }
    }

    // epilogue: w = wbase + m*16 + quad*4 + reg; cout n = wv*32 + nn*16 + (lane&15)
#pragma unroll
    for (int m = 0; m < 2; ++m) {
        const int w = wbase + (m << 4) + (quad << 2);
#pragma unroll
        for (int nn = 0; nn < 2; ++nn) {
            const int n = (wv << 5) + (nn << 4) + (lane & 15);
            float* op = out + (((size_t)((b << 8) + n)) << 12) + (h << 6) + w;
            *(f32x4*)op = acc[m][nn];
        }
    }
}

extern "C" void kernel_launch(void* const* d_in, const int* in_sizes, int n_in,
                              void* d_out, int out_size, void* d_ws, size_t ws_size,
                              hipStream_t stream) {
    const float* x      = (const float*)d_in[0];
    const float* w_off  = (const float*)d_in[1];
    const float* b_off  = (const float*)d_in[2];
    const float* w_conv = (const float*)d_in[3];
    float* out = (float*)d_out;

    const size_t need = 4194304ull * 4 + 663552ull * 2;   // 18,104,320 B
    const bool use_pair = (ws_size >= need);

    uint_t*   xpair = (uint_t*)d_ws;
    ushort_t* wfrag = use_pair ? (ushort_t*)((char*)d_ws + 4194304ull * 4)
                               : (ushort_t*)d_ws;
    const int XB = use_pair ? 512 : 0;

    hipLaunchKernelGGL(k_pre, dim3(XB + 162), dim3(512), 0, stream,
                       x, w_conv, w_off, wfrag, xpair, XB);
    if (use_pair)
        hipLaunchKernelGGL((k_all<true>), dim3(512), dim3(512), 0, stream,
                           x, xpair, b_off, wfrag, out);
    else
        hipLaunchKernelGGL((k_all<false>), dim3(512), dim3(512), 0, stream,
                           x, xpair, b_off, wfrag, out);
}